// Round 19
// baseline (361.523 us; speedup 1.0000x reference)
//
#include <hip/hip_runtime.h>

typedef unsigned short u16;
typedef unsigned int u32;
typedef __attribute__((ext_vector_type(8))) short bf16x8;
typedef __attribute__((ext_vector_type(4))) float f32x4;

__device__ __forceinline__ u16 f2bf(float f) {
  u32 u = __float_as_uint(f);
  u32 r = (u + 0x7FFFu + ((u >> 16) & 1u)) >> 16;  // RTNE
  return (u16)r;
}

__device__ __forceinline__ void gl_lds16(const u16* g, u16* l) {
  __builtin_amdgcn_global_load_lds(
      (const __attribute__((address_space(1))) u32*)g,
      (__attribute__((address_space(3))) u32*)l, 16, 0, 0);
}

// ---------------- prep: U fp32 -> bf16 ----------------
__global__ __launch_bounds__(256) void cvt_bf16(const float* __restrict__ src,
                                                u16* __restrict__ dst, int n4) {
  int g = blockIdx.x * 256 + threadIdx.x;
  if (g < n4) {
    float4 v = ((const float4*)src)[g];
    ushort4 o;
    o.x = f2bf(v.x); o.y = f2bf(v.y); o.z = f2bf(v.z); o.w = f2bf(v.w);
    ((ushort4*)dst)[g] = o;
  }
}

// ---------------- prep: x fp32 -> Xb bf16 [b][l][d] and XT bf16 [b][d][l] ----------------
__global__ __launch_bounds__(256) void prep_x(const float* __restrict__ x,
                                              u16* __restrict__ Xb,
                                              u16* __restrict__ XT) {
  __shared__ u16 t[32][33];
  const int b = blockIdx.z;
  const int l0 = blockIdx.y * 32;
  const int d0 = blockIdx.x * 32;
  const int j = threadIdx.x & 31;
  const int t5 = threadIdx.x >> 5;
#pragma unroll
  for (int r = 0; r < 4; r++) {
    int i = r * 8 + t5;
    float v = x[((size_t)b * 2048 + l0 + i) * 512 + d0 + j];
    u16 h = f2bf(v);
    t[i][j] = h;
    Xb[((size_t)b * 2048 + l0 + i) * 512 + d0 + j] = h;
  }
  __syncthreads();
#pragma unroll
  for (int r = 0; r < 4; r++) {
    int i = r * 8 + t5;
    XT[((size_t)b * 512 + d0 + i) * 2048 + l0 + j] = t[j][i];
  }
}

// ---------------- zred: z[i] = sum_j pz[j][i] (16 partials), fully coalesced ----------------
__global__ __launch_bounds__(256) void zred(const float* __restrict__ pz,
                                            float* __restrict__ z) {
  const int i = blockIdx.x * 256 + threadIdx.x;   // 0 .. 8*8192-1
  const int bz = i >> 13, row = i & 8191;
  const float* p = pz + (size_t)bz * 16 * 8192 + row;
  float s = 0.f;
#pragma unroll
  for (int j = 0; j < 16; j++) s += p[(size_t)j * 8192];
  z[i] = s;
}

// ---------------- gemm1: P[b] = bf16(exp(U @ x_b^T)), block-local z partials ----------------
// R16 inner loop/epilogue unchanged. NEW: batch-grouped XCD mapping (xcd = bzi)
// -> each XCD owns one batch; Xb[b] (2 MB) L2-resident for the whole kernel,
// same-byi U-panels shared within the XCD.
__global__ __launch_bounds__(256, 4)
void gemm1k(const u16* __restrict__ A, const u16* __restrict__ B,
            u16* __restrict__ P, float* __restrict__ pz, int nt,
            size_t Bb_str, size_t Cb_str, int gx, int gy) {
  __shared__ u16 lds[16384];   // A tile @0, B tile @8192; epilogue: 128x128 u16

  const int orig = blockIdx.x + gx * (blockIdx.y + gy * blockIdx.z);
  int bxi, byi, bzi;
  if (gridDim.z == 8) {
    // dispatch d = bzi + 8*(bxi + gx*byi): XCD (= d&7) == batch
    bzi = orig & 7;
    const int t = orig >> 3;
    bxi = t % gx;
    byi = t / gx;
  } else {
    const int nwg = gx * gy * gridDim.z;
    const int cpx = nwg >> 3;
    const int nid = (orig & 7) * cpx + (orig >> 3);
    bxi = nid % gx;
    byi = (nid / gx) % gy;
    bzi = nid / (gx * gy);
  }
  const int m0 = byi * 128, n0 = bxi * 128;

  const int tid = threadIdx.x;
  const int l = tid & 63;
  const int w = tid >> 6;
  const int wy = w >> 1, wx = w & 1;

  const int rowS = tid >> 3;
  const int cS = ((tid & 7) << 4) ^ ((rowS & 7) << 4);
  const u16* srcA0 = A + (size_t)(m0 + rowS) * 512 + (cS >> 1);
  const u16* srcB0 = B + (size_t)bzi * Bb_str + (size_t)(n0 + rowS) * 512 + (cS >> 1);
  const size_t rsk = (size_t)32 * 512;

  const int fr = l & 15;
  const int X = (fr & 7) << 4;
  const int kb = (l >> 4) << 4;
  const int swz0 = (kb ^ X) >> 1;
  const int swz1 = ((64 + kb) ^ X) >> 1;
  const int aRow = (wy * 64 + fr) * 64;
  const int bRow = (wx * 64 + fr) * 64;

  f32x4 acc[4][4] = {};

  for (int t = 0; t < nt; ++t) {
#pragma unroll
    for (int j = 0; j < 4; j++) {
      gl_lds16(srcA0 + j * rsk + t * 64, &lds[tid * 8 + j * 2048]);
      gl_lds16(srcB0 + j * rsk + t * 64, &lds[8192 + tid * 8 + j * 2048]);
    }
    __syncthreads();
#pragma unroll
    for (int ks = 0; ks < 2; ks++) {
      const int swz = ks ? swz1 : swz0;
      bf16x8 bfr[4], afr[4];
#pragma unroll
      for (int n = 0; n < 4; n++) bfr[n] = *(const bf16x8*)&lds[8192 + bRow + n * 1024 + swz];
#pragma unroll
      for (int m = 0; m < 4; m++) afr[m] = *(const bf16x8*)&lds[aRow + m * 1024 + swz];
#pragma unroll
      for (int m = 0; m < 4; m++)
#pragma unroll
        for (int n = 0; n < 4; n++)
          acc[m][n] = __builtin_amdgcn_mfma_f32_16x16x32_bf16(
              afr[m], bfr[n], acc[m][n], 0, 0, 0);
    }
    __syncthreads();
  }

  const int rq = (l >> 4) * 4;  // C/D: col=lane&15, row=(lane>>4)*4+reg
  float rsv[4][4];
#pragma unroll
  for (int m = 0; m < 4; m++) {
    const int lr0 = wy * 64 + m * 16 + rq;
    float rs[4] = {0.f, 0.f, 0.f, 0.f};
#pragma unroll
    for (int n = 0; n < 4; n++) {
      const int lc = wx * 64 + n * 16 + fr;
#pragma unroll
      for (int r = 0; r < 4; r++) {
        const float e = __expf(acc[m][n][r]);
        lds[(lr0 + r) * 128 + lc] = f2bf(e);
        rs[r] += e;
      }
    }
#pragma unroll
    for (int r = 0; r < 4; r++) rsv[m][r] = rs[r];
  }
  __syncthreads();
  u16* Pb = P + (size_t)bzi * Cb_str;
#pragma unroll
  for (int k = 0; k < 8; k++) {
    const int row = k * 16 + (tid >> 4);
    const int cu = (tid & 15) * 8;
    *(uint4*)&Pb[(size_t)(m0 + row) * 2048 + n0 + cu] = *(const uint4*)&lds[row * 128 + cu];
  }
  __syncthreads();

  float* pzl = (float*)lds;
#pragma unroll
  for (int m = 0; m < 4; m++)
#pragma unroll
    for (int r = 0; r < 4; r++)
      pzl[(wy * 64 + m * 16 + rq + r) * 33 + wx * 16 + fr] = rsv[m][r];
  __syncthreads();
  {
    const int row = tid >> 1, half = tid & 1;
    float s = 0.f;
#pragma unroll
    for (int j = 0; j < 16; j++) s += pzl[row * 33 + half * 16 + j];
    s += __shfl_xor(s, 1);
    if (!half) pz[((size_t)bzi * 16 + bxi) * 8192 + m0 + row] = s;
  }
}

// ---------------- gemm2: out[b] = (P[b] @ XT_b^T) / z[b] ----------------
// R18 inner loop unchanged. NEW: panel-grouped XCD mapping — the gx (=4)
// bx-blocks sharing one P row-panel (r = byi + gy*bzi) are dispatched at
// stride 8 onto the SAME XCD and run concurrently -> P panel fetched once
// into that L2 and K-streamed (working set ~1 MB << 4 MB). P L3 traffic /4.
__global__ __launch_bounds__(256, 4)
void gemm2k(const u16* __restrict__ A, const u16* __restrict__ B,
            float* __restrict__ Cout, const float* __restrict__ z,
            int Kstride, int nt, int N,
            size_t Ab_str, size_t Bb_str, size_t Cb_str, int gx, int gy) {
  __shared__ u16 lds[16384];
  __shared__ float rz_lds[128];

  const int orig = blockIdx.x + gx * (blockIdx.y + gy * blockIdx.z);
  int bxi, byi, bzi;
  if (gridDim.z == 8) {
    // dispatch d = (r&7) + 8*(bxi + gx*(r>>3)), r = byi + gy*bzi
    const int xcd = orig & 7;
    const int t = orig >> 3;
    bxi = t % gx;
    const int rr = t / gx;
    const int r = (rr << 3) | xcd;
    byi = r % gy;
    bzi = r / gy;
  } else {
    const int nwg = gx * gy * gridDim.z;
    const int cpx = nwg >> 3;
    const int nid = (orig & 7) * cpx + (orig >> 3);
    bxi = nid % gx;
    byi = (nid / gx) % gy;
    bzi = nid / (gx * gy);
  }
  const int m0 = byi * 128, n0 = bxi * 128;

  const u16* Ab = A + (size_t)bzi * Ab_str;
  const u16* Bb = B + (size_t)bzi * Bb_str;

  const int tid = threadIdx.x;
  const int l = tid & 63;
  const int w = tid >> 6;
  const int wy = w >> 1, wx = w & 1;

  const int rowS = tid >> 3;
  const int cS = ((tid & 7) << 4) ^ ((rowS & 7) << 4);
  const u16* srcA0 = Ab + (size_t)(m0 + rowS) * Kstride + (cS >> 1);
  const u16* srcB0 = Bb + (size_t)(n0 + rowS) * Kstride + (cS >> 1);
  const size_t rsk = (size_t)32 * Kstride;

  const int fr = l & 15;
  const int X = (fr & 7) << 4;
  const int kb = (l >> 4) << 4;
  const int swz0 = (kb ^ X) >> 1;
  const int swz1 = ((64 + kb) ^ X) >> 1;
  const int aRow = (wy * 64 + fr) * 64;
  const int bRow = (wx * 64 + fr) * 64;

  if (tid < 128) rz_lds[tid] = 1.f / z[(size_t)bzi * 8192 + m0 + tid];

  f32x4 acc[4][4] = {};

  for (int t = 0; t < nt; ++t) {
#pragma unroll
    for (int j = 0; j < 4; j++) {
      gl_lds16(srcA0 + j * rsk + t * 64, &lds[tid * 8 + j * 2048]);
      gl_lds16(srcB0 + j * rsk + t * 64, &lds[8192 + tid * 8 + j * 2048]);
    }
    __syncthreads();
#pragma unroll
    for (int ks = 0; ks < 2; ks++) {
      const int swz = ks ? swz1 : swz0;
      bf16x8 bfr[4], afr[4];
#pragma unroll
      for (int n = 0; n < 4; n++) bfr[n] = *(const bf16x8*)&lds[8192 + bRow + n * 1024 + swz];
#pragma unroll
      for (int m = 0; m < 4; m++) afr[m] = *(const bf16x8*)&lds[aRow + m * 1024 + swz];
#pragma unroll
      for (int m = 0; m < 4; m++)
#pragma unroll
        for (int n = 0; n < 4; n++)
          acc[m][n] = __builtin_amdgcn_mfma_f32_16x16x32_bf16(
              afr[m], bfr[n], acc[m][n], 0, 0, 0);
    }
    __syncthreads();
  }

  const int rq = (l >> 4) * 4;
#pragma unroll
  for (int m = 0; m < 4; m++) {
    const int lrow = wy * 64 + m * 16 + rq;
    const int grow = m0 + lrow;
#pragma unroll
    for (int n = 0; n < 4; n++) {
      const int col = n0 + wx * 64 + n * 16 + fr;
#pragma unroll
      for (int r = 0; r < 4; r++)
        Cout[(size_t)bzi * Cb_str + (size_t)(grow + r) * N + col] =
            acc[m][n][r] * rz_lds[lrow + r];
    }
  }
}

// B=8, L=2048, D=512, Y=8192
extern "C" void kernel_launch(void* const* d_in, const int* in_sizes, int n_in,
                              void* d_out, int out_size, void* d_ws, size_t ws_size,
                              hipStream_t stream) {
  const float* x = (const float*)d_in[0];   // [8][2048][512]
  const float* U = (const float*)d_in[1];   // [8192][512]
  if (n_in >= 2 && in_sizes[0] == 8192 * 512) {
    x = (const float*)d_in[1];
    U = (const float*)d_in[0];
  }
  float* out = (float*)d_out;               // [8][8192][512]
  char* ws = (char*)d_ws;

  // ws layout (bytes)
  u16* Ub = (u16*)ws;                            // 8 MiB
  u16* Xb = (u16*)(ws + 8388608);                // 16 MiB
  u16* XT = (u16*)(ws + 25165824);               // 16 MiB
  u16* P  = (u16*)(ws + 41943040);               // all-batch: 256 MiB
  float* pz = (float*)(ws + 41943040 + 268435456);          // 4 MiB
  float* z  = (float*)(ws + 41943040 + 268435456 + 4194304); // 256 KiB
  const size_t need_all = 41943040ull + 268435456ull + 4194304ull + 262144ull;

  cvt_bf16<<<4096, 256, 0, stream>>>(U, Ub, (8192 * 512) / 4);
  prep_x<<<dim3(16, 64, 8), 256, 0, stream>>>(x, Xb, XT);

  if (ws_size >= need_all) {
    // P[b] = exp(U @ x_b^T), block-local rowsum partials -> pz
    gemm1k<<<dim3(16, 64, 8), 256, 0, stream>>>(
        Ub, Xb, P, pz, 8, (size_t)2048 * 512, (size_t)8192 * 2048, 16, 64);
    // z = row-reduce of pz partials (coalesced, ~4us)
    zred<<<256, 256, 0, stream>>>(pz, z);
    // out[b] = (P[b] @ XT_b^T) / z[b]: M=8192, N=512, K=2048
    gemm2k<<<dim3(4, 64, 8), 256, 0, stream>>>(
        P, XT, out, z, 2048, 32, 512,
        (size_t)8192 * 2048, (size_t)512 * 2048, (size_t)8192 * 512, 4, 64);
  } else {
    // fallback: per-batch P (32 MiB); pz+z right after P
    u16* Pf = P;
    float* pzf = (float*)(ws + 41943040 + 33554432);
    float* zf = pzf + 16 * 8192;
    for (int b = 0; b < 8; b++) {
      gemm1k<<<dim3(16, 64, 1), 256, 0, stream>>>(
          Ub, Xb + (size_t)b * 2048 * 512, Pf, pzf, 8, 0, 0, 16, 64);
      zred<<<32, 256, 0, stream>>>(pzf, zf);
      gemm2k<<<dim3(4, 64, 1), 256, 0, stream>>>(
          Pf, XT + (size_t)b * 512 * 2048, out + (size_t)b * 8192 * 512,
          zf, 2048, 32, 512, 0, 0, 0, 4, 64);
    }
  }
}

// Round 20
// 355.468 us; speedup vs baseline: 1.0170x; 1.0170x over previous
//
#include <hip/hip_runtime.h>

typedef unsigned short u16;
typedef unsigned int u32;
typedef __attribute__((ext_vector_type(8))) short bf16x8;
typedef __attribute__((ext_vector_type(4))) float f32x4;

__device__ __forceinline__ u16 f2bf(float f) {
  u32 u = __float_as_uint(f);
  u32 r = (u + 0x7FFFu + ((u >> 16) & 1u)) >> 16;  // RTNE
  return (u16)r;
}

__device__ __forceinline__ void gl_lds16(const u16* g, u16* l) {
  __builtin_amdgcn_global_load_lds(
      (const __attribute__((address_space(1))) u32*)g,
      (__attribute__((address_space(3))) u32*)l, 16, 0, 0);
}

// ---------------- prep: U fp32 -> bf16 ----------------
__global__ __launch_bounds__(256) void cvt_bf16(const float* __restrict__ src,
                                                u16* __restrict__ dst, int n4) {
  int g = blockIdx.x * 256 + threadIdx.x;
  if (g < n4) {
    float4 v = ((const float4*)src)[g];
    ushort4 o;
    o.x = f2bf(v.x); o.y = f2bf(v.y); o.z = f2bf(v.z); o.w = f2bf(v.w);
    ((ushort4*)dst)[g] = o;
  }
}

// ---------------- prep: x fp32 -> Xb bf16 [b][l][d] and XT bf16 [b][d][l] ----------------
__global__ __launch_bounds__(256) void prep_x(const float* __restrict__ x,
                                              u16* __restrict__ Xb,
                                              u16* __restrict__ XT) {
  __shared__ u16 t[32][33];
  const int b = blockIdx.z;
  const int l0 = blockIdx.y * 32;
  const int d0 = blockIdx.x * 32;
  const int j = threadIdx.x & 31;
  const int t5 = threadIdx.x >> 5;
#pragma unroll
  for (int r = 0; r < 4; r++) {
    int i = r * 8 + t5;
    float v = x[((size_t)b * 2048 + l0 + i) * 512 + d0 + j];
    u16 h = f2bf(v);
    t[i][j] = h;
    Xb[((size_t)b * 2048 + l0 + i) * 512 + d0 + j] = h;
  }
  __syncthreads();
#pragma unroll
  for (int r = 0; r < 4; r++) {
    int i = r * 8 + t5;
    XT[((size_t)b * 512 + d0 + i) * 2048 + l0 + j] = t[j][i];
  }
}

// ---------------- gemm1: P[b] = bf16(exp(U @ x_b^T))  (R12-exact, 128us) ----------------
// 128x128 tile, BK=64, 4 waves 2x2, swizzled single-buffer LDS, 2-barrier
// K-loop, 4 blocks/CU. Epilogue: exp->bf16 tile into dead LDS -> coalesced
// dwordx4 stores. NO z work here (measured: every gemm1-side z variant costs
// 9-84us; gemm2's gated ones-MFMA is the cheapest z overall).
__global__ __launch_bounds__(256, 4)
void gemm1k(const u16* __restrict__ A, const u16* __restrict__ B,
            u16* __restrict__ P, int nt,
            size_t Bb_str, size_t Cb_str, int gx, int gy) {
  __shared__ u16 lds[16384];   // A tile @0, B tile @8192; epilogue: 128x128 u16

  const int nwg = gx * gy * gridDim.z;
  const int orig = blockIdx.x + gx * (blockIdx.y + gy * blockIdx.z);
  const int cpx = nwg >> 3;
  const int nid = (orig & 7) * cpx + (orig >> 3);
  const int bxi = nid % gx;
  const int byi = (nid / gx) % gy;
  const int bzi = nid / (gx * gy);
  const int m0 = byi * 128, n0 = bxi * 128;

  const int tid = threadIdx.x;
  const int l = tid & 63;
  const int w = tid >> 6;
  const int wy = w >> 1, wx = w & 1;

  const int rowS = tid >> 3;
  const int cS = ((tid & 7) << 4) ^ ((rowS & 7) << 4);
  const u16* srcA0 = A + (size_t)(m0 + rowS) * 512 + (cS >> 1);
  const u16* srcB0 = B + (size_t)bzi * Bb_str + (size_t)(n0 + rowS) * 512 + (cS >> 1);
  const size_t rsk = (size_t)32 * 512;

  const int fr = l & 15;
  const int X = (fr & 7) << 4;
  const int kb = (l >> 4) << 4;
  const int swz0 = (kb ^ X) >> 1;
  const int swz1 = ((64 + kb) ^ X) >> 1;
  const int aRow = (wy * 64 + fr) * 64;
  const int bRow = (wx * 64 + fr) * 64;

  f32x4 acc[4][4] = {};

  for (int t = 0; t < nt; ++t) {
#pragma unroll
    for (int j = 0; j < 4; j++) {
      gl_lds16(srcA0 + j * rsk + t * 64, &lds[tid * 8 + j * 2048]);
      gl_lds16(srcB0 + j * rsk + t * 64, &lds[8192 + tid * 8 + j * 2048]);
    }
    __syncthreads();
#pragma unroll
    for (int ks = 0; ks < 2; ks++) {
      const int swz = ks ? swz1 : swz0;
      bf16x8 bfr[4], afr[4];
#pragma unroll
      for (int n = 0; n < 4; n++) bfr[n] = *(const bf16x8*)&lds[8192 + bRow + n * 1024 + swz];
#pragma unroll
      for (int m = 0; m < 4; m++) afr[m] = *(const bf16x8*)&lds[aRow + m * 1024 + swz];
#pragma unroll
      for (int m = 0; m < 4; m++)
#pragma unroll
        for (int n = 0; n < 4; n++)
          acc[m][n] = __builtin_amdgcn_mfma_f32_16x16x32_bf16(
              afr[m], bfr[n], acc[m][n], 0, 0, 0);
    }
    __syncthreads();
  }

  // ---- epilogue: exp -> bf16 tile in LDS -> coalesced stores ----
  const int rq = (l >> 4) * 4;  // C/D: col=lane&15, row=(lane>>4)*4+reg
#pragma unroll
  for (int m = 0; m < 4; m++) {
    const int lr0 = wy * 64 + m * 16 + rq;
#pragma unroll
    for (int n = 0; n < 4; n++) {
      const int lc = wx * 64 + n * 16 + fr;
#pragma unroll
      for (int r = 0; r < 4; r++)
        lds[(lr0 + r) * 128 + lc] = f2bf(__expf(acc[m][n][r]));
    }
  }
  __syncthreads();
  u16* Pb = P + (size_t)bzi * Cb_str;
#pragma unroll
  for (int k = 0; k < 8; k++) {
    const int row = k * 16 + (tid >> 4);
    const int cu = (tid & 15) * 8;
    *(uint4*)&Pb[(size_t)(m0 + row) * 2048 + n0 + cu] = *(const uint4*)&lds[row * 128 + cu];
  }
}

// ---------------- gemm2: out[b] = (P[b] @ XT_b^T) / z, z via wx0-GATED ones-MFMA ----------------
// R12 main loop; the rowsum MFMA (B = ones) now issues only on the wx==0
// waves (wave-uniform branch): +12.5% matrix work on half the waves instead
// of +25% on all, absorbed at the tile barrier by the 4-block/CU mix. accz is
// column-independent, so wx0/fr==0 lanes publish 1/z to rz_lds post-loop.
__global__ __launch_bounds__(256, 4)
void gemm2k(const u16* __restrict__ A, const u16* __restrict__ B,
            float* __restrict__ Cout, int Kstride, int nt, int N,
            size_t Ab_str, size_t Bb_str, size_t Cb_str, int gx, int gy) {
  __shared__ u16 lds[16384];
  __shared__ float rz_lds[128];

  const int nwg = gx * gy * gridDim.z;
  const int orig = blockIdx.x + gx * (blockIdx.y + gy * blockIdx.z);
  const int cpx = nwg >> 3;
  const int nid = (orig & 7) * cpx + (orig >> 3);
  const int bxi = nid % gx;
  const int byi = (nid / gx) % gy;
  const int bzi = nid / (gx * gy);
  const int m0 = byi * 128, n0 = bxi * 128;

  const u16* Ab = A + (size_t)bzi * Ab_str;
  const u16* Bb = B + (size_t)bzi * Bb_str;

  const int tid = threadIdx.x;
  const int l = tid & 63;
  const int w = tid >> 6;
  const int wy = w >> 1, wx = w & 1;

  const int rowS = tid >> 3;
  const int cS = ((tid & 7) << 4) ^ ((rowS & 7) << 4);
  const u16* srcA0 = Ab + (size_t)(m0 + rowS) * Kstride + (cS >> 1);
  const u16* srcB0 = Bb + (size_t)(n0 + rowS) * Kstride + (cS >> 1);
  const size_t rsk = (size_t)32 * Kstride;

  const int fr = l & 15;
  const int X = (fr & 7) << 4;
  const int kb = (l >> 4) << 4;
  const int swz0 = (kb ^ X) >> 1;
  const int swz1 = ((64 + kb) ^ X) >> 1;
  const int aRow = (wy * 64 + fr) * 64;
  const int bRow = (wx * 64 + fr) * 64;

  bf16x8 onev;
#pragma unroll
  for (int i = 0; i < 8; i++) onev[i] = (short)0x3F80;  // bf16 1.0

  f32x4 acc[4][4] = {};
  f32x4 accz[4] = {};

  for (int t = 0; t < nt; ++t) {
#pragma unroll
    for (int j = 0; j < 4; j++) {
      gl_lds16(srcA0 + j * rsk + t * 64, &lds[tid * 8 + j * 2048]);
      gl_lds16(srcB0 + j * rsk + t * 64, &lds[8192 + tid * 8 + j * 2048]);
    }
    __syncthreads();
#pragma unroll
    for (int ks = 0; ks < 2; ks++) {
      const int swz = ks ? swz1 : swz0;
      bf16x8 bfr[4], afr[4];
#pragma unroll
      for (int n = 0; n < 4; n++) bfr[n] = *(const bf16x8*)&lds[8192 + bRow + n * 1024 + swz];
#pragma unroll
      for (int m = 0; m < 4; m++) afr[m] = *(const bf16x8*)&lds[aRow + m * 1024 + swz];
#pragma unroll
      for (int m = 0; m < 4; m++)
#pragma unroll
        for (int n = 0; n < 4; n++)
          acc[m][n] = __builtin_amdgcn_mfma_f32_16x16x32_bf16(
              afr[m], bfr[n], acc[m][n], 0, 0, 0);
      if (wx == 0) {  // wave-uniform: only 2 of 4 waves carry the z-MFMA
#pragma unroll
        for (int m = 0; m < 4; m++)
          accz[m] = __builtin_amdgcn_mfma_f32_16x16x32_bf16(afr[m], onev, accz[m], 0, 0, 0);
      }
    }
    __syncthreads();
  }

  const int rq = (l >> 4) * 4;
  // publish 1/z (accz is col-independent; fr==0 lanes write, others identical)
  if (wx == 0 && fr == 0) {
#pragma unroll
    for (int m = 0; m < 4; m++)
#pragma unroll
      for (int r = 0; r < 4; r++)
        rz_lds[wy * 64 + m * 16 + rq + r] = 1.f / accz[m][r];
  }
  __syncthreads();

#pragma unroll
  for (int m = 0; m < 4; m++) {
    const int lrow = wy * 64 + m * 16 + rq;
    const int grow = m0 + lrow;
#pragma unroll
    for (int n = 0; n < 4; n++) {
      const int col = n0 + wx * 64 + n * 16 + fr;
#pragma unroll
      for (int r = 0; r < 4; r++)
        Cout[(size_t)bzi * Cb_str + (size_t)(grow + r) * N + col] =
            acc[m][n][r] * rz_lds[lrow + r];
    }
  }
}

// B=8, L=2048, D=512, Y=8192
extern "C" void kernel_launch(void* const* d_in, const int* in_sizes, int n_in,
                              void* d_out, int out_size, void* d_ws, size_t ws_size,
                              hipStream_t stream) {
  const float* x = (const float*)d_in[0];   // [8][2048][512]
  const float* U = (const float*)d_in[1];   // [8192][512]
  if (n_in >= 2 && in_sizes[0] == 8192 * 512) {
    x = (const float*)d_in[1];
    U = (const float*)d_in[0];
  }
  float* out = (float*)d_out;               // [8][8192][512]
  char* ws = (char*)d_ws;

  // ws layout (bytes)
  u16* Ub = (u16*)ws;                       // 8 MiB
  u16* Xb = (u16*)(ws + 8388608);           // 16 MiB
  u16* XT = (u16*)(ws + 25165824);          // 16 MiB
  u16* P  = (u16*)(ws + 41943040);          // all-batch: 256 MiB
  const size_t need_all = 41943040ull + 268435456ull;

  cvt_bf16<<<4096, 256, 0, stream>>>(U, Ub, (8192 * 512) / 4);
  prep_x<<<dim3(16, 64, 8), 256, 0, stream>>>(x, Xb, XT);

  if (ws_size >= need_all) {
    // P[b] = exp(U @ x_b^T): M=8192, N=2048, K=512
    gemm1k<<<dim3(16, 64, 8), 256, 0, stream>>>(
        Ub, Xb, P, 8, (size_t)2048 * 512, (size_t)8192 * 2048, 16, 64);
    // out[b] = (P[b] @ XT_b^T) / rowsum(P[b]): M=8192, N=512, K=2048
    gemm2k<<<dim3(4, 64, 8), 256, 0, stream>>>(
        P, XT, out, 2048, 32, 512,
        (size_t)8192 * 2048, (size_t)512 * 2048, (size_t)8192 * 512, 4, 64);
  } else {
    // fallback: per-batch P (32 MiB)
    for (int b = 0; b < 8; b++) {
      gemm1k<<<dim3(16, 64, 1), 256, 0, stream>>>(
          Ub, Xb + (size_t)b * 2048 * 512, P, 8, 0, 0, 16, 64);
      gemm2k<<<dim3(4, 64, 1), 256, 0, stream>>>(
          P, XT + (size_t)b * 512 * 2048, out + (size_t)b * 8192 * 512,
          2048, 32, 512, 0, 0, 0, 4, 64);
    }
  }
}

// Round 21
// 341.780 us; speedup vs baseline: 1.0578x; 1.0400x over previous
//
#include <hip/hip_runtime.h>

typedef unsigned short u16;
typedef unsigned int u32;
typedef __attribute__((ext_vector_type(8))) short bf16x8;
typedef __attribute__((ext_vector_type(4))) float f32x4;

__device__ __forceinline__ u16 f2bf(float f) {
  u32 u = __float_as_uint(f);
  u32 r = (u + 0x7FFFu + ((u >> 16) & 1u)) >> 16;  // RTNE
  return (u16)r;
}

__device__ __forceinline__ void gl_lds16(const u16* g, u16* l) {
  __builtin_amdgcn_global_load_lds(
      (const __attribute__((address_space(1))) u32*)g,
      (__attribute__((address_space(3))) u32*)l, 16, 0, 0);
}

// ---------------- prep: U fp32 -> bf16 ----------------
__global__ __launch_bounds__(256) void cvt_bf16(const float* __restrict__ src,
                                                u16* __restrict__ dst, int n4) {
  int g = blockIdx.x * 256 + threadIdx.x;
  if (g < n4) {
    float4 v = ((const float4*)src)[g];
    ushort4 o;
    o.x = f2bf(v.x); o.y = f2bf(v.y); o.z = f2bf(v.z); o.w = f2bf(v.w);
    ((ushort4*)dst)[g] = o;
  }
}

// ---------------- prep: x fp32 -> Xb bf16 [b][l][d] and XT bf16 [b][d][l] ----------------
__global__ __launch_bounds__(256) void prep_x(const float* __restrict__ x,
                                              u16* __restrict__ Xb,
                                              u16* __restrict__ XT) {
  __shared__ u16 t[32][33];
  const int b = blockIdx.z;
  const int l0 = blockIdx.y * 32;
  const int d0 = blockIdx.x * 32;
  const int j = threadIdx.x & 31;
  const int t5 = threadIdx.x >> 5;
#pragma unroll
  for (int r = 0; r < 4; r++) {
    int i = r * 8 + t5;
    float v = x[((size_t)b * 2048 + l0 + i) * 512 + d0 + j];
    u16 h = f2bf(v);
    t[i][j] = h;
    Xb[((size_t)b * 2048 + l0 + i) * 512 + d0 + j] = h;
  }
  __syncthreads();
#pragma unroll
  for (int r = 0; r < 4; r++) {
    int i = r * 8 + t5;
    XT[((size_t)b * 512 + d0 + i) * 2048 + l0 + j] = t[j][i];
  }
}

// ---------------- zred: z[i] = sum_j pz[j][i] (16 partials), fully coalesced ----------------
__global__ __launch_bounds__(256) void zred(const float* __restrict__ pz,
                                            float* __restrict__ z) {
  const int i = blockIdx.x * 256 + threadIdx.x;   // 0 .. 8*8192-1
  const int bz = i >> 13, row = i & 8191;
  const float* p = pz + (size_t)bz * 16 * 8192 + row;
  float s = 0.f;
#pragma unroll
  for (int j = 0; j < 16; j++) s += p[(size_t)j * 8192];
  z[i] = s;
}

// ---------------- gemm1: P[b] = bf16(exp(U @ x_b^T)), block-local z partials ----------------
// R16-exact (measured 137us): 128x128 tile, BK=64, 4 waves 2x2, swizzled
// single-buffer LDS, 2-barrier K-loop, 4 blocks/CU; exp->bf16 tile in dead LDS
// -> coalesced stores; atomic-free pz partials via padded-LDS tail.
__global__ __launch_bounds__(256, 4)
void gemm1k(const u16* __restrict__ A, const u16* __restrict__ B,
            u16* __restrict__ P, float* __restrict__ pz, int nt,
            size_t Bb_str, size_t Cb_str, int gx, int gy) {
  __shared__ u16 lds[16384];   // A tile @0, B tile @8192; epilogue: 128x128 u16

  const int nwg = gx * gy * gridDim.z;
  const int orig = blockIdx.x + gx * (blockIdx.y + gy * blockIdx.z);
  const int cpx = nwg >> 3;
  const int nid = (orig & 7) * cpx + (orig >> 3);
  const int bxi = nid % gx;
  const int byi = (nid / gx) % gy;
  const int bzi = nid / (gx * gy);
  const int m0 = byi * 128, n0 = bxi * 128;

  const int tid = threadIdx.x;
  const int l = tid & 63;
  const int w = tid >> 6;
  const int wy = w >> 1, wx = w & 1;

  const int rowS = tid >> 3;
  const int cS = ((tid & 7) << 4) ^ ((rowS & 7) << 4);
  const u16* srcA0 = A + (size_t)(m0 + rowS) * 512 + (cS >> 1);
  const u16* srcB0 = B + (size_t)bzi * Bb_str + (size_t)(n0 + rowS) * 512 + (cS >> 1);
  const size_t rsk = (size_t)32 * 512;

  const int fr = l & 15;
  const int X = (fr & 7) << 4;
  const int kb = (l >> 4) << 4;
  const int swz0 = (kb ^ X) >> 1;
  const int swz1 = ((64 + kb) ^ X) >> 1;
  const int aRow = (wy * 64 + fr) * 64;
  const int bRow = (wx * 64 + fr) * 64;

  f32x4 acc[4][4] = {};

  for (int t = 0; t < nt; ++t) {
#pragma unroll
    for (int j = 0; j < 4; j++) {
      gl_lds16(srcA0 + j * rsk + t * 64, &lds[tid * 8 + j * 2048]);
      gl_lds16(srcB0 + j * rsk + t * 64, &lds[8192 + tid * 8 + j * 2048]);
    }
    __syncthreads();
#pragma unroll
    for (int ks = 0; ks < 2; ks++) {
      const int swz = ks ? swz1 : swz0;
      bf16x8 bfr[4], afr[4];
#pragma unroll
      for (int n = 0; n < 4; n++) bfr[n] = *(const bf16x8*)&lds[8192 + bRow + n * 1024 + swz];
#pragma unroll
      for (int m = 0; m < 4; m++) afr[m] = *(const bf16x8*)&lds[aRow + m * 1024 + swz];
#pragma unroll
      for (int m = 0; m < 4; m++)
#pragma unroll
        for (int n = 0; n < 4; n++)
          acc[m][n] = __builtin_amdgcn_mfma_f32_16x16x32_bf16(
              afr[m], bfr[n], acc[m][n], 0, 0, 0);
    }
    __syncthreads();
  }

  const int rq = (l >> 4) * 4;  // C/D: col=lane&15, row=(lane>>4)*4+reg
  float rsv[4][4];
#pragma unroll
  for (int m = 0; m < 4; m++) {
    const int lr0 = wy * 64 + m * 16 + rq;
    float rs[4] = {0.f, 0.f, 0.f, 0.f};
#pragma unroll
    for (int n = 0; n < 4; n++) {
      const int lc = wx * 64 + n * 16 + fr;
#pragma unroll
      for (int r = 0; r < 4; r++) {
        const float e = __expf(acc[m][n][r]);
        lds[(lr0 + r) * 128 + lc] = f2bf(e);
        rs[r] += e;
      }
    }
#pragma unroll
    for (int r = 0; r < 4; r++) rsv[m][r] = rs[r];
  }
  __syncthreads();
  u16* Pb = P + (size_t)bzi * Cb_str;
#pragma unroll
  for (int k = 0; k < 8; k++) {
    const int row = k * 16 + (tid >> 4);
    const int cu = (tid & 15) * 8;
    *(uint4*)&Pb[(size_t)(m0 + row) * 2048 + n0 + cu] = *(const uint4*)&lds[row * 128 + cu];
  }
  __syncthreads();

  float* pzl = (float*)lds;
#pragma unroll
  for (int m = 0; m < 4; m++)
#pragma unroll
    for (int r = 0; r < 4; r++)
      pzl[(wy * 64 + m * 16 + rq + r) * 33 + wx * 16 + fr] = rsv[m][r];
  __syncthreads();
  {
    const int row = tid >> 1, half = tid & 1;
    float s = 0.f;
#pragma unroll
    for (int j = 0; j < 16; j++) s += pzl[row * 33 + half * 16 + j];
    s += __shfl_xor(s, 1);
    if (!half) pz[((size_t)bzi * 16 + bxi) * 8192 + m0 + row] = s;
  }
}

// ---------------- gemm2: out[b] = (P[b] @ XT_b^T) / z[b] ----------------
// NEW: 128x256 tile, BK=64, 8 waves (2M x 4N, 64x64 each), 48.5 KB LDS,
// 3 blocks/CU (24 waves/CU). gx halves (2 vs 4) -> P re-staged 2x instead of
// 4x (1 GB -> 512 MB of P traffic); FLOP per staged byte x1.33. Per-wave
// inner loop identical to the verified 128^2 kernel (same swizzle: row
// r = j*64+rowS keeps (r&7)=(rowS&7)). z prebuilt (no z work, VGPR <= 128).
__global__ __launch_bounds__(512, 4)
void gemm2k(const u16* __restrict__ A, const u16* __restrict__ B,
            float* __restrict__ Cout, const float* __restrict__ z,
            int Kstride, int nt, int N,
            size_t Ab_str, size_t Bb_str, size_t Cb_str, int gx, int gy) {
  __shared__ u16 lds[24576];   // lA 128x64 @0 (8192 u16), lB 256x64 @8192 (16384 u16)
  __shared__ float rz_lds[128];

  const int nwg = gx * gy * gridDim.z;
  const int orig = blockIdx.x + gx * (blockIdx.y + gy * blockIdx.z);
  const int cpx = nwg >> 3;
  const int nid = (orig & 7) * cpx + (orig >> 3);
  const int bxi = nid % gx;
  const int byi = (nid / gx) % gy;
  const int bzi = nid / (gx * gy);
  const int m0 = byi * 128, n0 = bxi * 256;

  const u16* Ab = A + (size_t)bzi * Ab_str;
  const u16* Bb = B + (size_t)bzi * Bb_str;

  const int tid = threadIdx.x;
  const int l = tid & 63;
  const int w = tid >> 6;              // wave 0..7
  const int wm = w >> 2, wn = w & 3;   // 2(M) x 4(N), 64x64 per wave

  const int rowS = tid >> 3;           // 0..63
  const int cS = ((tid & 7) << 4) ^ ((rowS & 7) << 4);
  const u16* srcA0 = Ab + (size_t)(m0 + rowS) * Kstride + (cS >> 1);
  const u16* srcB0 = Bb + (size_t)(n0 + rowS) * Kstride + (cS >> 1);
  const size_t rsk = (size_t)64 * Kstride;   // 64-row chunk skip

  const int fr = l & 15;
  const int X = (fr & 7) << 4;
  const int kb = (l >> 4) << 4;
  const int swz0 = (kb ^ X) >> 1;
  const int swz1 = ((64 + kb) ^ X) >> 1;
  const int aRow = (wm * 64 + fr) * 64;          // lA: 128 rows
  const int bRow = 8192 + (wn * 64 + fr) * 64;   // lB: 256 rows @ u16 8192

  if (tid < 128) rz_lds[tid] = 1.f / z[(size_t)bzi * 8192 + m0 + tid];

  f32x4 acc[4][4] = {};

  for (int t = 0; t < nt; ++t) {
#pragma unroll
    for (int j = 0; j < 2; j++)
      gl_lds16(srcA0 + j * rsk + t * 64, &lds[tid * 8 + j * 4096]);
#pragma unroll
    for (int j = 0; j < 4; j++)
      gl_lds16(srcB0 + j * rsk + t * 64, &lds[8192 + tid * 8 + j * 4096]);
    __syncthreads();
#pragma unroll
    for (int ks = 0; ks < 2; ks++) {
      const int swz = ks ? swz1 : swz0;
      bf16x8 bfr[4], afr[4];
#pragma unroll
      for (int n = 0; n < 4; n++) bfr[n] = *(const bf16x8*)&lds[bRow + n * 1024 + swz];
#pragma unroll
      for (int m = 0; m < 4; m++) afr[m] = *(const bf16x8*)&lds[aRow + m * 1024 + swz];
#pragma unroll
      for (int m = 0; m < 4; m++)
#pragma unroll
        for (int n = 0; n < 4; n++)
          acc[m][n] = __builtin_amdgcn_mfma_f32_16x16x32_bf16(
              afr[m], bfr[n], acc[m][n], 0, 0, 0);
    }
    __syncthreads();
  }

  const int rq = (l >> 4) * 4;
#pragma unroll
  for (int m = 0; m < 4; m++) {
    const int lrow = wm * 64 + m * 16 + rq;
    const int grow = m0 + lrow;
#pragma unroll
    for (int n = 0; n < 4; n++) {
      const int col = n0 + wn * 64 + n * 16 + fr;
#pragma unroll
      for (int r = 0; r < 4; r++)
        Cout[(size_t)bzi * Cb_str + (size_t)(grow + r) * N + col] =
            acc[m][n][r] * rz_lds[lrow + r];
    }
  }
}

// B=8, L=2048, D=512, Y=8192
extern "C" void kernel_launch(void* const* d_in, const int* in_sizes, int n_in,
                              void* d_out, int out_size, void* d_ws, size_t ws_size,
                              hipStream_t stream) {
  const float* x = (const float*)d_in[0];   // [8][2048][512]
  const float* U = (const float*)d_in[1];   // [8192][512]
  if (n_in >= 2 && in_sizes[0] == 8192 * 512) {
    x = (const float*)d_in[1];
    U = (const float*)d_in[0];
  }
  float* out = (float*)d_out;               // [8][8192][512]
  char* ws = (char*)d_ws;

  // ws layout (bytes)
  u16* Ub = (u16*)ws;                            // 8 MiB
  u16* Xb = (u16*)(ws + 8388608);                // 16 MiB
  u16* XT = (u16*)(ws + 25165824);               // 16 MiB
  u16* P  = (u16*)(ws + 41943040);               // all-batch: 256 MiB
  float* pz = (float*)(ws + 41943040 + 268435456);          // 4 MiB
  float* z  = (float*)(ws + 41943040 + 268435456 + 4194304); // 256 KiB
  const size_t need_all = 41943040ull + 268435456ull + 4194304ull + 262144ull;

  cvt_bf16<<<4096, 256, 0, stream>>>(U, Ub, (8192 * 512) / 4);
  prep_x<<<dim3(16, 64, 8), 256, 0, stream>>>(x, Xb, XT);

  if (ws_size >= need_all) {
    // P[b] = exp(U @ x_b^T), block-local rowsum partials -> pz
    gemm1k<<<dim3(16, 64, 8), 256, 0, stream>>>(
        Ub, Xb, P, pz, 8, (size_t)2048 * 512, (size_t)8192 * 2048, 16, 64);
    // z = row-reduce of pz partials (coalesced, ~4us)
    zred<<<256, 256, 0, stream>>>(pz, z);
    // out[b] = (P[b] @ XT_b^T) / z[b]: M=8192, N=512 (256-wide tiles), K=2048
    gemm2k<<<dim3(2, 64, 8), 512, 0, stream>>>(
        P, XT, out, z, 2048, 32, 512,
        (size_t)8192 * 2048, (size_t)512 * 2048, (size_t)8192 * 512, 2, 64);
  } else {
    // fallback: per-batch P (32 MiB); pz+z right after P
    u16* Pf = P;
    float* pzf = (float*)(ws + 41943040 + 33554432);
    float* zf = pzf + 16 * 8192;
    for (int b = 0; b < 8; b++) {
      gemm1k<<<dim3(16, 64, 1), 256, 0, stream>>>(
          Ub, Xb + (size_t)b * 2048 * 512, Pf, pzf, 8, 0, 0, 16, 64);
      zred<<<32, 256, 0, stream>>>(pzf, zf);
      gemm2k<<<dim3(2, 64, 1), 512, 0, stream>>>(
          Pf, XT + (size_t)b * 512 * 2048, out + (size_t)b * 8192 * 512,
          zf, 2048, 32, 512, 0, 0, 0, 2, 64);
    }
  }
}